// Round 1
// baseline (1856.011 us; speedup 1.0000x reference)
//
#include <hip/hip_runtime.h>
#include <math.h>

#define B_DIM 2048
#define V_DIM 4096
#define H_DIM 1024

// fp32 accumulation emulating OpenBLAS sgemm GEBP: strictly k-sequential FMA
// within KC=384 panels, panel partials combined by fold-left fp32 add.
// (VERIFIED bit-exact vs numpy reference — per-element arithmetic order is
//  load-bearing; do not alter.)
//
// Round 5: LDS-pipe was the bottleneck (17.2 GB LDS reads/GEMM ≈ measured
// 264/210 us). 8x8 microtile on 128x128 tiles halves ds_read instrs per FMA.
// gemm_h gets panel-aligned split-K (one block per KC panel, 11 panels) +
// ordered combine kernel to restore grid parallelism; combine folds panel
// partials in ascending panel order = bitwise-identical to the old in-kernel
// tot accumulation. gemm_v stays fused (tot+part dual accumulators).
#define BM 128
#define BN 128
#define BK 16
#define KC 384            // OpenBLAS SGEMM_DEFAULT_Q
#define NPANEL_H 11       // ceil(V_DIM / KC): 10 x 384 + 256
#define LDSS 132          // 128+4, float4-aligned stride

enum { ACC_NONE = 0, ACC_PREACT = 1, ACC_BIAS = 2 };

// ---------------------------------------------------------------------------
// Split-K partial GEMM for h-side: P[panel][b][j] = sum_{k in panel} A[b,k]*W[k,j]
// Strictly k-ascending FMA chain from 0.0f within the panel (bit-exact).
// ---------------------------------------------------------------------------
__global__ __launch_bounds__(256) void gemm_h_panel(
    const float* __restrict__ A,   // [B_DIM, V_DIM]
    const float* __restrict__ W,   // [V_DIM, H_DIM] row-major
    float* __restrict__ P)         // [NPANEL_H, B_DIM, H_DIM]
{
    __shared__ float As[2][BK][LDSS];
    __shared__ float Bs[2][BK][LDSS];

    const int bn  = blockIdx.x * BN;   // H cols
    const int bm  = blockIdx.y * BM;   // B rows
    const int pan = blockIdx.z;        // KC panel
    const int k0  = pan * KC;
    const int klen = (V_DIM - k0 < KC) ? (V_DIM - k0) : KC;  // 384 or 256
    const int T = klen / BK;                                  // 24 or 16

    const int t  = threadIdx.x;
    const int tx = t & 15;
    const int ty = t >> 4;

    // staging maps
    const int s_ar = t >> 1;          // A: row 0..127
    const int s_ak = (t & 1) * 8;     // A: k-half 0 or 8
    const int s_bc = (t & 31) * 4;    // B: col*4 0..124
    const int s_bk = t >> 5;          // B: k 0..7 (and +8)

    const float* Aptr = A + (size_t)(bm + s_ar) * V_DIM + k0 + s_ak;
    const float* Wptr = W + (size_t)(k0 + s_bk) * H_DIM + bn + s_bc;

    float part[8][8];
#pragma unroll
    for (int i = 0; i < 8; i++)
#pragma unroll
        for (int j = 0; j < 8; j++) part[i][j] = 0.0f;

    // prologue: tile 0 -> buffer 0
    float4 a0 = *(const float4*)(Aptr + 0);
    float4 a1 = *(const float4*)(Aptr + 4);
    float4 w0 = *(const float4*)(Wptr);
    float4 w1 = *(const float4*)(Wptr + (size_t)8 * H_DIM);
    As[0][s_ak + 0][s_ar] = a0.x;
    As[0][s_ak + 1][s_ar] = a0.y;
    As[0][s_ak + 2][s_ar] = a0.z;
    As[0][s_ak + 3][s_ar] = a0.w;
    As[0][s_ak + 4][s_ar] = a1.x;
    As[0][s_ak + 5][s_ar] = a1.y;
    As[0][s_ak + 6][s_ar] = a1.z;
    As[0][s_ak + 7][s_ar] = a1.w;
    *(float4*)(&Bs[0][s_bk][s_bc])     = w0;
    *(float4*)(&Bs[0][s_bk + 8][s_bc]) = w1;

    int cur = 0;
    for (int it = 0; it < T; ++it) {
        __syncthreads();
        if (it + 1 < T) {
            const int kk = (it + 1) * BK;
            a0 = *(const float4*)(Aptr + kk);
            a1 = *(const float4*)(Aptr + kk + 4);
            w0 = *(const float4*)(Wptr + (size_t)kk * H_DIM);
            w1 = *(const float4*)(Wptr + (size_t)(kk + 8) * H_DIM);
        }
#pragma unroll
        for (int k = 0; k < BK; k++) {
            float4 xa = *(const float4*)(&As[cur][k][ty * 4]);
            float4 xb = *(const float4*)(&As[cur][k][64 + ty * 4]);
            float4 ya = *(const float4*)(&Bs[cur][k][tx * 4]);
            float4 yb = *(const float4*)(&Bs[cur][k][64 + tx * 4]);
            float aa[8] = {xa.x, xa.y, xa.z, xa.w, xb.x, xb.y, xb.z, xb.w};
            float bb[8] = {ya.x, ya.y, ya.z, ya.w, yb.x, yb.y, yb.z, yb.w};
#pragma unroll
            for (int i = 0; i < 8; i++)
#pragma unroll
                for (int j = 0; j < 8; j++)
                    part[i][j] = fmaf(aa[i], bb[j], part[i][j]);
        }
        if (it + 1 < T) {
            As[cur ^ 1][s_ak + 0][s_ar] = a0.x;
            As[cur ^ 1][s_ak + 1][s_ar] = a0.y;
            As[cur ^ 1][s_ak + 2][s_ar] = a0.z;
            As[cur ^ 1][s_ak + 3][s_ar] = a0.w;
            As[cur ^ 1][s_ak + 4][s_ar] = a1.x;
            As[cur ^ 1][s_ak + 5][s_ar] = a1.y;
            As[cur ^ 1][s_ak + 6][s_ar] = a1.z;
            As[cur ^ 1][s_ak + 7][s_ar] = a1.w;
            *(float4*)(&Bs[cur ^ 1][s_bk][s_bc])     = w0;
            *(float4*)(&Bs[cur ^ 1][s_bk + 8][s_bc]) = w1;
        }
        cur ^= 1;
    }

    float* Pout = P + (size_t)pan * B_DIM * H_DIM;
#pragma unroll
    for (int i = 0; i < 8; i++) {
        const int row = bm + ((i < 4) ? (ty * 4 + i) : (64 + ty * 4 + (i - 4)));
        float4 lo, hi;
        lo.x = part[i][0]; lo.y = part[i][1]; lo.z = part[i][2]; lo.w = part[i][3];
        hi.x = part[i][4]; hi.y = part[i][5]; hi.z = part[i][6]; hi.w = part[i][7];
        *(float4*)(&Pout[(size_t)row * H_DIM + bn + tx * 4])      = lo;
        *(float4*)(&Pout[(size_t)row * H_DIM + bn + 64 + tx * 4]) = hi;
    }
}

// ---------------------------------------------------------------------------
// Ordered panel-fold + epilogue for h-side: tot = ((p0+p1)+...)+p10 (fp32,
// ascending panel order — identical to old in-kernel tot), then
// pre = bh + tot; h = (sigmoid(pre) > U). One block per batch row.
// ---------------------------------------------------------------------------
__global__ __launch_bounds__(256) void combine_h(
    const float* __restrict__ P,   // [NPANEL_H, B_DIM, H_DIM]
    const float* __restrict__ bh,  // [H_DIM]
    const float* __restrict__ U,   // [B_DIM, H_DIM]
    float* __restrict__ Hout,      // [B_DIM, H_DIM]
    double* __restrict__ acc,      // [B_DIM] direct store (single writer) or nullptr
    const int mode)
{
    const int b = blockIdx.x;
    const int c = threadIdx.x * 4;                 // 256*4 = 1024 = H_DIM
    const size_t BH  = (size_t)B_DIM * H_DIM;
    const size_t off = (size_t)b * H_DIM + c;

    float4 tot = *(const float4*)(P + off);        // = 0.0f + p0 (exact)
#pragma unroll
    for (int p = 1; p < NPANEL_H; p++) {
        float4 q = *(const float4*)(P + (size_t)p * BH + off);
        tot.x += q.x; tot.y += q.y; tot.z += q.z; tot.w += q.w;
    }
    float4 bias = *(const float4*)(bh + c);
    float4 u    = *(const float4*)(U + off);

    float pre[4] = {bias.x + tot.x, bias.y + tot.y, bias.z + tot.z, bias.w + tot.w};
    float bb[4]  = {bias.x, bias.y, bias.z, bias.w};
    float uu[4]  = {u.x, u.y, u.z, u.w};
    float hv[4];
#pragma unroll
    for (int j = 0; j < 4; j++) {
        float pp = 1.0f / (1.0f + expf(-pre[j]));   // fp32 pipeline, numpy order
        hv[j] = (pp > uu[j]) ? 1.0f : 0.0f;
    }
    float4 hout; hout.x = hv[0]; hout.y = hv[1]; hout.z = hv[2]; hout.w = hv[3];
    *(float4*)(Hout + off) = hout;

    if (mode != ACC_NONE) {
        double s = 0.0;
#pragma unroll
        for (int j = 0; j < 4; j++) {
            if (mode == ACC_PREACT) s += (double)hv[j] * (double)pre[j];
            else                    s += (double)hv[j] * (double)bb[j];
        }
#pragma unroll
        for (int offl = 32; offl >= 1; offl >>= 1) s += __shfl_xor(s, offl, 64);
        __shared__ double red[4];
        if ((threadIdx.x & 63) == 0) red[threadIdx.x >> 6] = s;
        __syncthreads();
        if (threadIdx.x == 0) acc[b] = red[0] + red[1] + red[2] + red[3];
    }
}

// ---------------------------------------------------------------------------
// v-side GEMM (h @ W^T), fused epilogue. 128x128 tile, 8x8 microtile,
// in-kernel KC-panel fold (tot/part) preserved bit-exact.
// ---------------------------------------------------------------------------
__global__ __launch_bounds__(256) void gemm_v_kernel(
    const float* __restrict__ A,   // [B_DIM, H_DIM]
    const float* __restrict__ W,   // [V_DIM, H_DIM] row-major
    const float* __restrict__ bv,  // [V_DIM]
    const float* __restrict__ U,   // [B_DIM, V_DIM]
    float* __restrict__ Vout,      // [B_DIM, V_DIM]
    double* __restrict__ acc,      // [B_DIM] (atomic) or nullptr
    const int mode)
{
    __shared__ float As[2][BK][LDSS];
    __shared__ float Bs[2][BK][LDSS];

    const int bn = blockIdx.x * BN;   // V cols
    const int bm = blockIdx.y * BM;   // B rows
    const int t  = threadIdx.x;
    const int tx = t & 15;
    const int ty = t >> 4;

    const int s_ar = t >> 1;
    const int s_ak = (t & 1) * 8;

    const float* Aptr = A + (size_t)(bm + s_ar) * H_DIM + s_ak;
    const float* Wrow = W + (size_t)(bn + s_ar) * H_DIM + s_ak;

    float tot[8][8];
    float part[8][8];
#pragma unroll
    for (int i = 0; i < 8; i++)
#pragma unroll
        for (int j = 0; j < 8; j++) { tot[i][j] = 0.0f; part[i][j] = 0.0f; }

    // prologue: tile 0 -> buffer 0
    float4 a0 = *(const float4*)(Aptr + 0);
    float4 a1 = *(const float4*)(Aptr + 4);
    float4 w0 = *(const float4*)(Wrow + 0);
    float4 w1 = *(const float4*)(Wrow + 4);
    As[0][s_ak + 0][s_ar] = a0.x;
    As[0][s_ak + 1][s_ar] = a0.y;
    As[0][s_ak + 2][s_ar] = a0.z;
    As[0][s_ak + 3][s_ar] = a0.w;
    As[0][s_ak + 4][s_ar] = a1.x;
    As[0][s_ak + 5][s_ar] = a1.y;
    As[0][s_ak + 6][s_ar] = a1.z;
    As[0][s_ak + 7][s_ar] = a1.w;
    Bs[0][s_ak + 0][s_ar] = w0.x;
    Bs[0][s_ak + 1][s_ar] = w0.y;
    Bs[0][s_ak + 2][s_ar] = w0.z;
    Bs[0][s_ak + 3][s_ar] = w0.w;
    Bs[0][s_ak + 4][s_ar] = w1.x;
    Bs[0][s_ak + 5][s_ar] = w1.y;
    Bs[0][s_ak + 6][s_ar] = w1.z;
    Bs[0][s_ak + 7][s_ar] = w1.w;

    const int T = H_DIM / BK;   // 64
    int cur = 0;
    for (int it = 0; it < T; ++it) {
        __syncthreads();
        if (it + 1 < T) {
            const int kk = (it + 1) * BK;
            a0 = *(const float4*)(Aptr + kk);
            a1 = *(const float4*)(Aptr + kk + 4);
            w0 = *(const float4*)(Wrow + kk);
            w1 = *(const float4*)(Wrow + kk + 4);
        }
#pragma unroll
        for (int k = 0; k < BK; k++) {
            float4 xa = *(const float4*)(&As[cur][k][ty * 4]);
            float4 xb = *(const float4*)(&As[cur][k][64 + ty * 4]);
            float4 ya = *(const float4*)(&Bs[cur][k][tx * 4]);
            float4 yb = *(const float4*)(&Bs[cur][k][64 + tx * 4]);
            float aa[8] = {xa.x, xa.y, xa.z, xa.w, xb.x, xb.y, xb.z, xb.w};
            float bb[8] = {ya.x, ya.y, ya.z, ya.w, yb.x, yb.y, yb.z, yb.w};
#pragma unroll
            for (int i = 0; i < 8; i++)
#pragma unroll
                for (int j = 0; j < 8; j++)
                    part[i][j] = fmaf(aa[i], bb[j], part[i][j]);
        }
        if (it + 1 < T) {
            As[cur ^ 1][s_ak + 0][s_ar] = a0.x;
            As[cur ^ 1][s_ak + 1][s_ar] = a0.y;
            As[cur ^ 1][s_ak + 2][s_ar] = a0.z;
            As[cur ^ 1][s_ak + 3][s_ar] = a0.w;
            As[cur ^ 1][s_ak + 4][s_ar] = a1.x;
            As[cur ^ 1][s_ak + 5][s_ar] = a1.y;
            As[cur ^ 1][s_ak + 6][s_ar] = a1.z;
            As[cur ^ 1][s_ak + 7][s_ar] = a1.w;
            Bs[cur ^ 1][s_ak + 0][s_ar] = w0.x;
            Bs[cur ^ 1][s_ak + 1][s_ar] = w0.y;
            Bs[cur ^ 1][s_ak + 2][s_ar] = w0.z;
            Bs[cur ^ 1][s_ak + 3][s_ar] = w0.w;
            Bs[cur ^ 1][s_ak + 4][s_ar] = w1.x;
            Bs[cur ^ 1][s_ak + 5][s_ar] = w1.y;
            Bs[cur ^ 1][s_ak + 6][s_ar] = w1.z;
            Bs[cur ^ 1][s_ak + 7][s_ar] = w1.w;
        }
        cur ^= 1;
        if ((((it + 1) * BK) % KC) == 0) {   // end of a KC panel
#pragma unroll
            for (int i = 0; i < 8; i++)
#pragma unroll
                for (int j = 0; j < 8; j++) { tot[i][j] += part[i][j]; part[i][j] = 0.0f; }
        }
    }
    if ((H_DIM % KC) != 0) {                 // trailing panel (256)
#pragma unroll
        for (int i = 0; i < 8; i++)
#pragma unroll
            for (int j = 0; j < 8; j++) tot[i][j] += part[i][j];
    }

    double rowacc[8] = {0, 0, 0, 0, 0, 0, 0, 0};
#pragma unroll
    for (int i = 0; i < 8; i++) {
        const int row = bm + ((i < 4) ? (ty * 4 + i) : (64 + ty * 4 + (i - 4)));
#pragma unroll
        for (int jj = 0; jj < 2; jj++) {
            const int col0 = bn + ((jj == 0) ? (tx * 4) : (64 + tx * 4));
            float4 u4 = *(const float4*)(&U[(size_t)row * V_DIM + col0]);
            float uu[4] = {u4.x, u4.y, u4.z, u4.w};
            float4 vstore;
            float vs[4];
#pragma unroll
            for (int j = 0; j < 4; j++) {
                float pre = bv[col0 + j] + tot[i][jj * 4 + j];
                float p = 1.0f / (1.0f + expf(-pre));
                float vv = (p > uu[j]) ? 1.0f : 0.0f;
                vs[j] = vv;
                if (mode == ACC_PREACT) rowacc[i] += (double)vv * (double)pre;
            }
            vstore.x = vs[0]; vstore.y = vs[1]; vstore.z = vs[2]; vstore.w = vs[3];
            *(float4*)(&Vout[(size_t)row * V_DIM + col0]) = vstore;
        }
    }
    if (mode != ACC_NONE) {
#pragma unroll
        for (int off = 8; off >= 1; off >>= 1)
#pragma unroll
            for (int i = 0; i < 8; i++)
                rowacc[i] += __shfl_xor(rowacc[i], off, 16);
        if (tx == 0) {
#pragma unroll
            for (int i = 0; i < 8; i++) {
                const int row = bm + ((i < 4) ? (ty * 4 + i) : (64 + ty * 4 + (i - 4)));
                atomicAdd(&acc[row], rowacc[i]);
            }
        }
    }
}

// out[b] = sum_i X[b,i] * w[i] in fp64 (score term; does not feed sampling)
__global__ __launch_bounds__(256) void rowdot_kernel(
    const float* __restrict__ X, const float* __restrict__ w,
    double* __restrict__ out, const int N)
{
    const int b = blockIdx.x;
    const float* row = X + (size_t)b * N;
    double s = 0.0;
    for (int i = threadIdx.x; i < N / 4; i += blockDim.x) {
        float4 x = ((const float4*)row)[i];
        float4 ww = ((const float4*)w)[i];
        s = fma((double)x.x, (double)ww.x, s);
        s = fma((double)x.y, (double)ww.y, s);
        s = fma((double)x.z, (double)ww.z, s);
        s = fma((double)x.w, (double)ww.w, s);
    }
#pragma unroll
    for (int off = 32; off >= 1; off >>= 1) s += __shfl_xor(s, off, 64);
    __shared__ double red[4];
    if ((threadIdx.x & 63) == 0) red[threadIdx.x >> 6] = s;
    __syncthreads();
    if (threadIdx.x == 0) out[b] = red[0] + red[1] + red[2] + red[3];
}

__global__ void finalize_kernel(const double* __restrict__ vb,
                                const double* __restrict__ accpos,
                                const double* __restrict__ acchb,
                                const double* __restrict__ accneg,
                                float* __restrict__ out)
{
    int b = blockIdx.x * blockDim.x + threadIdx.x;
    if (b < B_DIM) out[b] = (float)(vb[b] + accpos[b] - acchb[b] - accneg[b]);
}

extern "C" void kernel_launch(void* const* d_in, const int* in_sizes, int n_in,
                              void* d_out, int out_size, void* d_ws, size_t ws_size,
                              hipStream_t stream) {
    (void)in_sizes; (void)n_in; (void)out_size; (void)ws_size;
    const float* visible = (const float*)d_in[0];
    const float* b_v     = (const float*)d_in[1];
    const float* b_h     = (const float*)d_in[2];
    const float* W       = (const float*)d_in[3];
    const float* u_h0    = (const float*)d_in[4];
    const float* u_v     = (const float*)d_in[5];  // [3, B, V]
    const float* u_h     = (const float*)d_in[6];  // [2, B, H]
    float* out = (float*)d_out;

    float* v_buf   = (float*)d_ws;                               // B*V floats
    float* h_buf   = v_buf + (size_t)B_DIM * V_DIM;              // B*H floats
    double* acc_pos = (double*)(h_buf + (size_t)B_DIM * H_DIM);  // B doubles
    double* acc_hb  = acc_pos + B_DIM;
    double* acc_neg = acc_hb + B_DIM;
    double* vb      = acc_neg + B_DIM;
    float* Ppart    = (float*)(vb + B_DIM);          // NPANEL_H * B * H floats (~92 MB)

    // only acc_neg is accumulated via atomics; acc_pos/acc_hb are direct stores
    hipMemsetAsync(acc_neg, 0, B_DIM * sizeof(double), stream);

    dim3 blk(256);
    dim3 gh(H_DIM / BN, B_DIM / BM, NPANEL_H);   // 8 x 16 x 11 = 1408 blocks
    dim3 gv(V_DIM / BN, B_DIM / BM);             // 32 x 16 = 512 blocks
    dim3 gc(B_DIM);                              // combine: one block per row

    rowdot_kernel<<<B_DIM, blk, 0, stream>>>(visible, b_v, vb, V_DIM);

    const size_t UV = (size_t)B_DIM * V_DIM;
    const size_t UH = (size_t)B_DIM * H_DIM;

    // positive phase: h | data, + sum h*pre
    gemm_h_panel<<<gh, blk, 0, stream>>>(visible, W, Ppart);
    combine_h<<<gc, blk, 0, stream>>>(Ppart, b_h, u_h0, h_buf, acc_pos, ACC_PREACT);
    // k=0
    gemm_v_kernel<<<gv, blk, 0, stream>>>(h_buf, W, b_v, u_v + 0 * UV, v_buf, nullptr, ACC_NONE);
    // k=1
    gemm_h_panel<<<gh, blk, 0, stream>>>(v_buf, W, Ppart);
    combine_h<<<gc, blk, 0, stream>>>(Ppart, b_h, u_h + 0 * UH, h_buf, nullptr, ACC_NONE);
    // k=2
    gemm_v_kernel<<<gv, blk, 0, stream>>>(h_buf, W, b_v, u_v + 1 * UV, v_buf, nullptr, ACC_NONE);
    // k=3: + h.b_h of final h
    gemm_h_panel<<<gh, blk, 0, stream>>>(v_buf, W, Ppart);
    combine_h<<<gc, blk, 0, stream>>>(Ppart, b_h, u_h + 1 * UH, h_buf, acc_hb, ACC_BIAS);
    // k=4: + sum_i v*pre (negative score)
    gemm_v_kernel<<<gv, blk, 0, stream>>>(h_buf, W, b_v, u_v + 2 * UV, v_buf, acc_neg, ACC_PREACT);

    finalize_kernel<<<(B_DIM + 255) / 256, blk, 0, stream>>>(vb, acc_pos, acc_hb, acc_neg, out);
}